// Round 1
// baseline (4054.224 us; speedup 1.0000x reference)
//
#include <hip/hip_runtime.h>
#include <cmath>

#define K_IN 64
#define K_OUT 64
#define K_STATE 256
#define T_PRE 64
#define T_FWD 80
#define BATCH 4096

// ---- ws layout (float offsets) ----
// WrnnT [384][256]: rows 0..255 = W_hh^T, rows 256..383 = W_ih^T  (K-order: h, then xy)
// WssT  [320][256]: rows 0..255 = A_w^T,  rows 256..319 = B_w^T   (K-order: h, then x)
// CT    [256][64] : C_w^T
// brnn  [256]     : b_ih + b_hh
// bss   [256]     : A_b + B_b
#define OFF_WRNN 0
#define OFF_WSS  98304
#define OFF_CT   180224
#define OFF_BRNN 196608
#define OFF_BSS  196864
#define WS_FLOATS 197120

__global__ void prep_kernel(const float* __restrict__ A_w, const float* __restrict__ A_b,
                            const float* __restrict__ B_w, const float* __restrict__ B_b,
                            const float* __restrict__ C_w,
                            const float* __restrict__ W_ih, const float* __restrict__ b_ih,
                            const float* __restrict__ W_hh, const float* __restrict__ b_hh,
                            float* __restrict__ ws) {
  int i = blockIdx.x * blockDim.x + threadIdx.x;
  if (i >= WS_FLOATS) return;
  float v;
  if (i < OFF_WSS) {                       // WrnnT
    int k = i >> 8, j = i & 255;
    v = (k < 256) ? W_hh[j * 256 + k] : W_ih[j * 128 + (k - 256)];
  } else if (i < OFF_CT) {                 // WssT
    int ii = i - OFF_WSS;
    int k = ii >> 8, j = ii & 255;
    v = (k < 256) ? A_w[j * 256 + k] : B_w[j * 64 + (k - 256)];
  } else if (i < OFF_BRNN) {               // CT
    int ii = i - OFF_CT;
    int k = ii >> 6, o = ii & 63;
    v = C_w[o * 256 + k];
  } else if (i < OFF_BSS) {
    int j = i - OFF_BRNN;
    v = b_ih[j] + b_hh[j];
  } else {
    int j = i - OFF_BSS;
    v = A_b[j] + B_b[j];
  }
  ws[i] = v;
}

// stage one [32][256] chunk of W^T into LDS (32 KB), coalesced float4
__device__ __forceinline__ void stage_w(float* __restrict__ wbuf,
                                        const float* __restrict__ src, int tid) {
  const float4* s4 = (const float4*)src;
  float4* d4 = (float4*)wbuf;
#pragma unroll
  for (int u = 0; u < 8; ++u) d4[tid + u * 256] = s4[tid + u * 256];
}

// 16x256 output tile, 4x4 per thread, one K-chunk of 32
__device__ __forceinline__ void gemm_chunk(const float* __restrict__ xh,
                                           const float* __restrict__ wbuf,
                                           float acc[4][4], int ty, int tx, int kbase) {
#pragma unroll
  for (int kk = 0; kk < 32; kk += 4) {
    float a[4][4];
#pragma unroll
    for (int rr = 0; rr < 4; ++rr) {
      float4 t = *(const float4*)&xh[(ty * 4 + rr) * 384 + kbase + kk];
      a[rr][0] = t.x; a[rr][1] = t.y; a[rr][2] = t.z; a[rr][3] = t.w;
    }
#pragma unroll
    for (int u = 0; u < 4; ++u) {
      float4 b = *(const float4*)&wbuf[(kk + u) * 256 + tx * 4];
#pragma unroll
      for (int rr = 0; rr < 4; ++rr) {
        acc[rr][0] += a[rr][u] * b.x;
        acc[rr][1] += a[rr][u] * b.y;
        acc[rr][2] += a[rr][u] * b.z;
        acc[rr][3] += a[rr][u] * b.w;
      }
    }
  }
}

// Persistent kernel: 256 blocks x 16 batch rows. LDS xh row layout:
// [0..255] = h, [256..319] = x, [320..383] = y (RNN) / unused (SS).
__global__ __launch_bounds__(256) void rnn_ss_kernel(
    const float* __restrict__ pre_x, const float* __restrict__ pre_y,
    const float* __restrict__ fwd_x, const float* __restrict__ ws,
    const float* __restrict__ C_b, float* __restrict__ out) {
  __shared__ float xh[16 * 384];    // 24 KB
  __shared__ float wbuf[32 * 256];  // 32 KB

  const float* wrnnT = ws + OFF_WRNN;
  const float* wssT  = ws + OFF_WSS;
  const float* ct    = ws + OFF_CT;
  const float* brnn  = ws + OFF_BRNN;
  const float* bss   = ws + OFF_BSS;

  const int tid = threadIdx.x;
  const int tx = tid & 63;   // column group: cols tx*4 .. tx*4+3
  const int ty = tid >> 6;   // row group: rows ty*4 .. ty*4+3
  const int r0 = blockIdx.x * 16;
  const int lr = tid >> 4;   // loader row 0..15
  const int lc = tid & 15;   // loader float4-col 0..15

  for (int i = tid; i < 16 * 384; i += 256) xh[i] = 0.0f;  // h0 = 0

  const float4 bias_r = ((const float4*)brnn)[tx];
  const float4 bias_s = ((const float4*)bss)[tx];

  // ---------------- encoder tanh-RNN ----------------
  for (int t = 0; t < T_PRE; ++t) {
    __syncthreads();  // prev h-write / zero-init visible; prev compute done reading x
    {
      const float4 vx = *(const float4*)(pre_x + ((size_t)t * BATCH + r0 + lr) * K_IN + lc * 4);
      const float4 vy = *(const float4*)(pre_y + ((size_t)t * BATCH + r0 + lr) * K_OUT + lc * 4);
      *(float4*)&xh[lr * 384 + 256 + lc * 4] = vx;
      *(float4*)&xh[lr * 384 + 320 + lc * 4] = vy;
    }
    float acc[4][4];
#pragma unroll
    for (int rr = 0; rr < 4; ++rr) {
      acc[rr][0] = bias_r.x; acc[rr][1] = bias_r.y;
      acc[rr][2] = bias_r.z; acc[rr][3] = bias_r.w;
    }
    for (int c = 0; c < 12; ++c) {  // K = 384
      __syncthreads();
      stage_w(wbuf, wrnnT + c * 32 * 256, tid);
      __syncthreads();
      gemm_chunk(xh, wbuf, acc, ty, tx, c * 32);
    }
    __syncthreads();  // all reads of old h done
#pragma unroll
    for (int rr = 0; rr < 4; ++rr) {
      float4 hv = make_float4(tanhf(acc[rr][0]), tanhf(acc[rr][1]),
                              tanhf(acc[rr][2]), tanhf(acc[rr][3]));
      *(float4*)&xh[(ty * 4 + rr) * 384 + tx * 4] = hv;
    }
  }

  // ---------------- state-space rollout + output ----------------
  const float4* ct4 = (const float4*)ct;
  const float4 cb = ((const float4*)C_b)[lc];
  for (int t = 0; t < T_FWD; ++t) {
    __syncthreads();
    {
      const float4 vx = *(const float4*)(fwd_x + ((size_t)t * BATCH + r0 + lr) * K_IN + lc * 4);
      *(float4*)&xh[lr * 384 + 256 + lc * 4] = vx;
    }
    float acc[4][4];
#pragma unroll
    for (int rr = 0; rr < 4; ++rr) {
      acc[rr][0] = bias_s.x; acc[rr][1] = bias_s.y;
      acc[rr][2] = bias_s.z; acc[rr][3] = bias_s.w;
    }
    for (int c = 0; c < 10; ++c) {  // K = 320
      __syncthreads();
      stage_w(wbuf, wssT + c * 32 * 256, tid);
      __syncthreads();
      gemm_chunk(xh, wbuf, acc, ty, tx, c * 32);
    }
    __syncthreads();
#pragma unroll
    for (int rr = 0; rr < 4; ++rr) {
      float4 hv = make_float4(acc[rr][0], acc[rr][1], acc[rr][2], acc[rr][3]);
      *(float4*)&xh[(ty * 4 + rr) * 384 + tx * 4] = hv;
    }
    __syncthreads();
    // y_t[r][lc*4..+3] = h_t[r] . C^T + C_b
    float4 accy = cb;
#pragma unroll 4
    for (int k = 0; k < 256; k += 4) {
      float4 av4 = *(const float4*)&xh[lr * 384 + k];
      float a4[4] = {av4.x, av4.y, av4.z, av4.w};
#pragma unroll
      for (int u = 0; u < 4; ++u) {
        float4 cw = ct4[(k + u) * 16 + lc];
        accy.x += a4[u] * cw.x;
        accy.y += a4[u] * cw.y;
        accy.z += a4[u] * cw.z;
        accy.w += a4[u] * cw.w;
      }
    }
    *(float4*)(out + ((size_t)t * BATCH + r0 + lr) * K_OUT + lc * 4) = accy;
  }
}

extern "C" void kernel_launch(void* const* d_in, const int* in_sizes, int n_in,
                              void* d_out, int out_size, void* d_ws, size_t ws_size,
                              hipStream_t stream) {
  const float* pre_x = (const float*)d_in[0];
  const float* pre_y = (const float*)d_in[1];
  const float* fwd_x = (const float*)d_in[2];
  const float* A_w   = (const float*)d_in[3];
  const float* A_b   = (const float*)d_in[4];
  const float* B_w   = (const float*)d_in[5];
  const float* B_b   = (const float*)d_in[6];
  const float* C_w   = (const float*)d_in[7];
  const float* C_b   = (const float*)d_in[8];
  const float* W_ih  = (const float*)d_in[9];
  const float* b_ih  = (const float*)d_in[10];
  const float* W_hh  = (const float*)d_in[11];
  const float* b_hh  = (const float*)d_in[12];
  float* ws  = (float*)d_ws;
  float* out = (float*)d_out;

  prep_kernel<<<(WS_FLOATS + 255) / 256, 256, 0, stream>>>(
      A_w, A_b, B_w, B_b, C_w, W_ih, b_ih, W_hh, b_hh, ws);
  rnn_ss_kernel<<<BATCH / 16, 256, 0, stream>>>(pre_x, pre_y, fwd_x, ws, C_b, out);
}

// Round 2
// 316.351 us; speedup vs baseline: 12.8156x; 12.8156x over previous
//
#include <hip/hip_runtime.h>

typedef __attribute__((ext_vector_type(8))) short short8;
typedef __attribute__((ext_vector_type(4))) float f32x4;

#define T_PRE 64
#define T_FWD 80
#define BATCHN 4096
#define PITCH 392  // bf16 elems per xh row (384 + 8 pad)

// ---- ws layout (ushort offsets) ----
// wrnn [256][384] bf16 : rows j = [W_hh[j][0..255] | W_ih[j][0..127]]
// wss  [256][320] bf16 : rows j = [A_w[j][0..255]  | B_w[j][0..63]]
// c    [64][256]  bf16 : C_w
// then floats: brnn[256] = b_ih+b_hh, bss[256] = A_b+B_b
#define U_WRNN 0
#define U_WSS  98304
#define U_C    180224
#define U_END  196608
#define PREP_N 197120

__device__ __forceinline__ unsigned short bf1(float a) {
  unsigned ua = __float_as_uint(a);
  return (unsigned short)((ua + 0x7fffu + ((ua >> 16) & 1u)) >> 16);
}
__device__ __forceinline__ unsigned bfpack(float a, float b) {
  unsigned ua = __float_as_uint(a), ub = __float_as_uint(b);
  ua = (ua + 0x7fffu + ((ua >> 16) & 1u)) >> 16;
  ub = (ub + 0x7fffu + ((ub >> 16) & 1u)) >> 16;
  return ua | (ub << 16);
}
__device__ __forceinline__ float tanh_fast(float x) {
  float e = __expf(2.0f * x);  // large |x| saturates correctly (inf -> 1, 0 -> -1)
  return 1.0f - 2.0f * __builtin_amdgcn_rcpf(e + 1.0f);
}

__global__ void prep_kernel(const float* __restrict__ A_w, const float* __restrict__ A_b,
                            const float* __restrict__ B_w, const float* __restrict__ B_b,
                            const float* __restrict__ C_w,
                            const float* __restrict__ W_ih, const float* __restrict__ b_ih,
                            const float* __restrict__ W_hh, const float* __restrict__ b_hh,
                            unsigned short* __restrict__ ws) {
  int i = blockIdx.x * 256 + threadIdx.x;
  if (i < U_WSS) {
    int j = i / 384, k = i - j * 384;
    float v = (k < 256) ? W_hh[j * 256 + k] : W_ih[j * 128 + (k - 256)];
    ws[i] = bf1(v);
  } else if (i < U_C) {
    int ii = i - U_WSS;
    int j = ii / 320, k = ii - j * 320;
    float v = (k < 256) ? A_w[j * 256 + k] : B_w[j * 64 + (k - 256)];
    ws[i] = bf1(v);
  } else if (i < U_END) {
    int ii = i - U_C;
    int o = ii >> 8, k = ii & 255;
    ws[i] = bf1(C_w[o * 256 + k]);
  } else if (i < PREP_N) {
    float* fb = (float*)(ws + U_END);
    int j = i - U_END;
    fb[j] = (j < 256) ? (b_ih[j] + b_hh[j]) : (A_b[j - 256] + B_b[j - 256]);
  }
}

// Persistent: 256 blocks x 16 batch rows. xh[b][k] bf16, k: 0..255=h, 256..383=inputs.
// MFMA transposed: A = weight rows (register-resident), B = xh, D cols = batch.
__global__ __launch_bounds__(256, 1) void rnn_ss_kernel(
    const float* __restrict__ pre_x, const float* __restrict__ pre_y,
    const float* __restrict__ fwd_x, const float* __restrict__ C_b,
    const unsigned short* __restrict__ ws, float* __restrict__ out) {
  __shared__ unsigned short xh[16 * PITCH];

  const int tid = threadIdx.x;
  const int lane = tid & 63;
  const int w = tid >> 6;      // wave: owns states [w*64, w*64+64), y-outs [w*16, w*16+16)
  const int col = lane & 15;   // A row within tile / B batch col / D batch col
  const int q = lane >> 4;     // quad
  const int r0 = blockIdx.x * 16;
  const int srow = tid >> 4;   // staging: batch row 0..15
  const int sc4 = tid & 15;    // staging: float4 col 0..15

  // zero h region (k = 0..255) -> h0 = 0
  {
    unsigned* p = (unsigned*)xh;
#pragma unroll
    for (int it = 0; it < 8; ++it) {
      int i = tid + it * 256;
      int r = i >> 7, c = i & 127;
      p[r * (PITCH / 2) + c] = 0u;
    }
  }

  const float* fbias = (const float*)(ws + U_END);

  // ---------------- encoder tanh-RNN (K = 384) ----------------
  {
    short8 wf[4][12];
#pragma unroll
    for (int mt = 0; mt < 4; ++mt)
#pragma unroll
      for (int kf = 0; kf < 12; ++kf)
        wf[mt][kf] = *(const short8*)(ws + U_WRNN +
                       (size_t)(w * 64 + mt * 16 + col) * 384 + kf * 32 + q * 8);
    f32x4 br[4];
#pragma unroll
    for (int mt = 0; mt < 4; ++mt)
      br[mt] = *(const f32x4*)(fbias + w * 64 + mt * 16 + q * 4);

    // stage xy_0
    {
      f32x4 px = *(const f32x4*)(pre_x + (size_t)(r0 + srow) * 64 + sc4 * 4);
      f32x4 py = *(const f32x4*)(pre_y + (size_t)(r0 + srow) * 64 + sc4 * 4);
      *(uint2*)&xh[srow * PITCH + 256 + sc4 * 4] = make_uint2(bfpack(px[0], px[1]), bfpack(px[2], px[3]));
      *(uint2*)&xh[srow * PITCH + 320 + sc4 * 4] = make_uint2(bfpack(py[0], py[1]), bfpack(py[2], py[3]));
    }

    for (int t = 0; t < T_PRE; ++t) {
      f32x4 npx, npy;
      if (t < T_PRE - 1) {
        npx = *(const f32x4*)(pre_x + ((size_t)(t + 1) * BATCHN + r0 + srow) * 64 + sc4 * 4);
        npy = *(const f32x4*)(pre_y + ((size_t)(t + 1) * BATCHN + r0 + srow) * 64 + sc4 * 4);
      }
      __syncthreads();  // h_{t-1}, xy_t visible
      short8 bfr[12];
#pragma unroll
      for (int kf = 0; kf < 12; ++kf)
        bfr[kf] = *(const short8*)&xh[col * PITCH + kf * 32 + q * 8];
      f32x4 acc[4];
#pragma unroll
      for (int mt = 0; mt < 4; ++mt) acc[mt] = br[mt];
#pragma unroll
      for (int kf = 0; kf < 12; ++kf)
#pragma unroll
        for (int mt = 0; mt < 4; ++mt)
          acc[mt] = __builtin_amdgcn_mfma_f32_16x16x32_bf16(wf[mt][kf], bfr[kf], acc[mt], 0, 0, 0);
      __syncthreads();  // all reads of xh done
#pragma unroll
      for (int mt = 0; mt < 4; ++mt) {
        float t0 = tanh_fast(acc[mt][0]), t1 = tanh_fast(acc[mt][1]);
        float t2 = tanh_fast(acc[mt][2]), t3 = tanh_fast(acc[mt][3]);
        *(uint2*)&xh[col * PITCH + w * 64 + mt * 16 + q * 4] =
            make_uint2(bfpack(t0, t1), bfpack(t2, t3));
      }
      if (t < T_PRE - 1) {
        *(uint2*)&xh[srow * PITCH + 256 + sc4 * 4] = make_uint2(bfpack(npx[0], npx[1]), bfpack(npx[2], npx[3]));
        *(uint2*)&xh[srow * PITCH + 320 + sc4 * 4] = make_uint2(bfpack(npy[0], npy[1]), bfpack(npy[2], npy[3]));
      }
    }
  }

  // ---------------- state-space rollout (K = 320) + fused y = C h ----------------
  {
    short8 sf[4][10];
#pragma unroll
    for (int mt = 0; mt < 4; ++mt)
#pragma unroll
      for (int kf = 0; kf < 10; ++kf)
        sf[mt][kf] = *(const short8*)(ws + U_WSS +
                       (size_t)(w * 64 + mt * 16 + col) * 320 + kf * 32 + q * 8);
    short8 cf[8];
#pragma unroll
    for (int kf = 0; kf < 8; ++kf)
      cf[kf] = *(const short8*)(ws + U_C + (size_t)(w * 16 + col) * 256 + kf * 32 + q * 8);
    f32x4 bs[4];
#pragma unroll
    for (int mt = 0; mt < 4; ++mt)
      bs[mt] = *(const f32x4*)(fbias + 256 + w * 64 + mt * 16 + q * 4);
    f32x4 cb = *(const f32x4*)(C_b + w * 16 + q * 4);

    // stage x for step 1 (fwd_x[0]); h_0 = hn already in xh
    {
      f32x4 fx = *(const f32x4*)(fwd_x + (size_t)(r0 + srow) * 64 + sc4 * 4);
      *(uint2*)&xh[srow * PITCH + 256 + sc4 * 4] = make_uint2(bfpack(fx[0], fx[1]), bfpack(fx[2], fx[3]));
    }

    for (int i = 0; i < T_FWD; ++i) {
      f32x4 nfx;
      if (i < T_FWD - 1)
        nfx = *(const f32x4*)(fwd_x + ((size_t)(i + 1) * BATCHN + r0 + srow) * 64 + sc4 * 4);
      __syncthreads();  // h_i, x_{i+1} visible
      short8 bfr[10];
#pragma unroll
      for (int kf = 0; kf < 10; ++kf)
        bfr[kf] = *(const short8*)&xh[col * PITCH + kf * 32 + q * 8];
      f32x4 acc[4];
#pragma unroll
      for (int mt = 0; mt < 4; ++mt) acc[mt] = bs[mt];
#pragma unroll
      for (int kf = 0; kf < 10; ++kf)
#pragma unroll
        for (int mt = 0; mt < 4; ++mt)
          acc[mt] = __builtin_amdgcn_mfma_f32_16x16x32_bf16(sf[mt][kf], bfr[kf], acc[mt], 0, 0, 0);
      if (i >= 1) {  // y_i = C h_i + C_b, reuses this step's B-fragments
        f32x4 y = cb;
#pragma unroll
        for (int kf = 0; kf < 8; ++kf)
          y = __builtin_amdgcn_mfma_f32_16x16x32_bf16(cf[kf], bfr[kf], y, 0, 0, 0);
        *(f32x4*)(out + ((size_t)(i - 1) * BATCHN + r0 + col) * 64 + w * 16 + q * 4) = y;
      }
      __syncthreads();  // reads done before overwriting h
#pragma unroll
      for (int mt = 0; mt < 4; ++mt)
        *(uint2*)&xh[col * PITCH + w * 64 + mt * 16 + q * 4] =
            make_uint2(bfpack(acc[mt][0], acc[mt][1]), bfpack(acc[mt][2], acc[mt][3]));
      if (i < T_FWD - 1)
        *(uint2*)&xh[srow * PITCH + 256 + sc4 * 4] = make_uint2(bfpack(nfx[0], nfx[1]), bfpack(nfx[2], nfx[3]));
    }

    // epilogue: y_80 from h_80
    __syncthreads();
    {
      short8 bfr[8];
#pragma unroll
      for (int kf = 0; kf < 8; ++kf)
        bfr[kf] = *(const short8*)&xh[col * PITCH + kf * 32 + q * 8];
      f32x4 y = cb;
#pragma unroll
      for (int kf = 0; kf < 8; ++kf)
        y = __builtin_amdgcn_mfma_f32_16x16x32_bf16(cf[kf], bfr[kf], y, 0, 0, 0);
      *(f32x4*)(out + ((size_t)(T_FWD - 1) * BATCHN + r0 + col) * 64 + w * 16 + q * 4) = y;
    }
  }
}

extern "C" void kernel_launch(void* const* d_in, const int* in_sizes, int n_in,
                              void* d_out, int out_size, void* d_ws, size_t ws_size,
                              hipStream_t stream) {
  const float* pre_x = (const float*)d_in[0];
  const float* pre_y = (const float*)d_in[1];
  const float* fwd_x = (const float*)d_in[2];
  const float* A_w   = (const float*)d_in[3];
  const float* A_b   = (const float*)d_in[4];
  const float* B_w   = (const float*)d_in[5];
  const float* B_b   = (const float*)d_in[6];
  const float* C_w   = (const float*)d_in[7];
  const float* C_b   = (const float*)d_in[8];
  const float* W_ih  = (const float*)d_in[9];
  const float* b_ih  = (const float*)d_in[10];
  const float* W_hh  = (const float*)d_in[11];
  const float* b_hh  = (const float*)d_in[12];
  unsigned short* ws = (unsigned short*)d_ws;
  float* out = (float*)d_out;

  prep_kernel<<<(PREP_N + 255) / 256, 256, 0, stream>>>(
      A_w, A_b, B_w, B_b, C_w, W_ih, b_ih, W_hh, b_hh, ws);
  rnn_ss_kernel<<<BATCHN / 16, 256, 0, stream>>>(pre_x, pre_y, fwd_x, C_b, ws, out);
}

// Round 3
// 298.414 us; speedup vs baseline: 13.5859x; 1.0601x over previous
//
#include <hip/hip_runtime.h>
#include <hip/hip_bf16.h>

typedef __attribute__((ext_vector_type(8))) short short8;
typedef __attribute__((ext_vector_type(4))) float f32x4;

#define T_PRE 64
#define T_FWD 80
#define BATCHN 4096

#define HP 264   // h row pitch (bf16 elems): 256 + 8 pad
#define IP 136   // input row pitch: 128 + 8 pad

// ---- ws layout (ushort offsets) ----
// wrnn [256][384] bf16 : rows j = [W_hh[j][0..255] | W_ih[j][0..127]]
// wss  [256][320] bf16 : rows j = [A_w[j][0..255]  | B_w[j][0..63]]
// c    [64][256]  bf16 : C_w
// then floats: brnn[256] = b_ih+b_hh, bss[256] = A_b+B_b
#define U_WRNN 0
#define U_WSS  98304
#define U_C    180224
#define U_END  196608
#define PREP_N 197120

__device__ __forceinline__ unsigned short bf1(float a) {
  unsigned ua = __float_as_uint(a);
  return (unsigned short)((ua + 0x7fffu + ((ua >> 16) & 1u)) >> 16);
}
__device__ __forceinline__ unsigned pk(float a, float b) {
  __hip_bfloat162 h = __float22bfloat162_rn(make_float2(a, b));
  unsigned u;
  __builtin_memcpy(&u, &h, 4);
  return u;
}
__device__ __forceinline__ float tanh_fast(float x) {
  float e = __expf(2.0f * x);  // saturates correctly for large |x|
  return 1.0f - 2.0f * __builtin_amdgcn_rcpf(e + 1.0f);
}

__global__ void prep_kernel(const float* __restrict__ A_w, const float* __restrict__ A_b,
                            const float* __restrict__ B_w, const float* __restrict__ B_b,
                            const float* __restrict__ C_w,
                            const float* __restrict__ W_ih, const float* __restrict__ b_ih,
                            const float* __restrict__ W_hh, const float* __restrict__ b_hh,
                            unsigned short* __restrict__ ws) {
  int i = blockIdx.x * 256 + threadIdx.x;
  if (i < U_WSS) {
    int j = i / 384, k = i - j * 384;
    float v = (k < 256) ? W_hh[j * 256 + k] : W_ih[j * 128 + (k - 256)];
    ws[i] = bf1(v);
  } else if (i < U_C) {
    int ii = i - U_WSS;
    int j = ii / 320, k = ii - j * 320;
    float v = (k < 256) ? A_w[j * 256 + k] : B_w[j * 64 + (k - 256)];
    ws[i] = bf1(v);
  } else if (i < U_END) {
    int ii = i - U_C;
    int o = ii >> 8, k = ii & 255;
    ws[i] = bf1(C_w[o * 256 + k]);
  } else if (i < PREP_N) {
    float* fb = (float*)(ws + U_END);
    int j = i - U_END;
    fb[j] = (j < 256) ? (b_ih[j] + b_hh[j]) : (A_b[j - 256] + B_b[j - 256]);
  }
}

// Persistent: 256 blocks x 16 batch rows, 512 threads (8 waves, 2/SIMD).
// Wave w owns states [w*32, w*32+32). Double-buffered h + inputs -> 1 barrier/step.
// MFMA: A = weight rows (register-resident), B = xh (batch cols), D cols = batch.
__global__ __launch_bounds__(512, 1) void rnn_ss_kernel(
    const float* __restrict__ pre_x, const float* __restrict__ pre_y,
    const float* __restrict__ fwd_x, const float* __restrict__ C_b,
    const unsigned short* __restrict__ ws, float* __restrict__ out) {
  __shared__ unsigned short hbuf[2][16 * HP];
  __shared__ unsigned short ibuf[2][16 * IP];

  const int tid = threadIdx.x;
  const int lane = tid & 63;
  const int w = tid >> 6;      // wave 0..7
  const int col = lane & 15;   // batch col (B/D) / A row-in-tile
  const int q = lane >> 4;     // quad
  const int r0 = blockIdx.x * 16;
  const int srow = (tid & 255) >> 4;  // staging batch row 0..15
  const int sc4 = tid & 15;           // staging float4 col 0..15
  const bool xhalf = (tid >= 256);    // waves 4-7 stage x; waves 0-3 stage y (RNN)

  // zero hbuf[0] h region (16 rows x 256 elems) -> h0 = 0
#pragma unroll
  for (int it = 0; it < 2; ++it) {
    int i = tid + it * 512;
    int r = i >> 6, c = (i & 63) * 4;
    *(uint2*)&hbuf[0][r * HP + c] = make_uint2(0u, 0u);
  }

  const float* fbias = (const float*)(ws + U_END);
  int cur = 0;

  // ---------------- encoder tanh-RNN (K = 384) ----------------
  {
    short8 wf[2][12];
#pragma unroll
    for (int mt = 0; mt < 2; ++mt)
#pragma unroll
      for (int kf = 0; kf < 12; ++kf)
        wf[mt][kf] = *(const short8*)(ws + U_WRNN +
                       (size_t)(w * 32 + mt * 16 + col) * 384 + kf * 32 + q * 8);
    f32x4 br[2];
#pragma unroll
    for (int mt = 0; mt < 2; ++mt)
      br[mt] = *(const f32x4*)(fbias + w * 32 + mt * 16 + q * 4);

    // stage xy_0 into ibuf[0]
    {
      f32x4 v = xhalf ? *(const f32x4*)(pre_x + (size_t)(r0 + srow) * 64 + sc4 * 4)
                      : *(const f32x4*)(pre_y + (size_t)(r0 + srow) * 64 + sc4 * 4);
      *(uint2*)&ibuf[0][srow * IP + (xhalf ? 0 : 64) + sc4 * 4] =
          make_uint2(pk(v[0], v[1]), pk(v[2], v[3]));
    }

    for (int t = 0; t < T_PRE; ++t) {
      f32x4 nv;
      bool do_stage = true;
      if (t < T_PRE - 1) {
        nv = xhalf ? *(const f32x4*)(pre_x + ((size_t)(t + 1) * BATCHN + r0 + srow) * 64 + sc4 * 4)
                   : *(const f32x4*)(pre_y + ((size_t)(t + 1) * BATCHN + r0 + srow) * 64 + sc4 * 4);
      } else if (xhalf) {
        nv = *(const f32x4*)(fwd_x + (size_t)(r0 + srow) * 64 + sc4 * 4);  // fwd_x[0]
      } else {
        do_stage = false;
      }
      __syncthreads();  // h_t (hbuf[cur]) and xy_t (ibuf[cur]) visible
      const unsigned short* hc = hbuf[cur];
      const unsigned short* ic = ibuf[cur];
      short8 bfr[12];
#pragma unroll
      for (int kf = 0; kf < 8; ++kf)
        bfr[kf] = *(const short8*)&hc[col * HP + kf * 32 + q * 8];
#pragma unroll
      for (int kf = 8; kf < 12; ++kf)
        bfr[kf] = *(const short8*)&ic[col * IP + (kf - 8) * 32 + q * 8];
      f32x4 acc[2];
#pragma unroll
      for (int mt = 0; mt < 2; ++mt) acc[mt] = br[mt];
#pragma unroll
      for (int kf = 0; kf < 12; ++kf)
#pragma unroll
        for (int mt = 0; mt < 2; ++mt)
          acc[mt] = __builtin_amdgcn_mfma_f32_16x16x32_bf16(wf[mt][kf], bfr[kf], acc[mt], 0, 0, 0);
      unsigned short* hn_ = hbuf[cur ^ 1];
#pragma unroll
      for (int mt = 0; mt < 2; ++mt) {
        float t0 = tanh_fast(acc[mt][0]), t1 = tanh_fast(acc[mt][1]);
        float t2 = tanh_fast(acc[mt][2]), t3 = tanh_fast(acc[mt][3]);
        *(uint2*)&hn_[col * HP + w * 32 + mt * 16 + q * 4] =
            make_uint2(pk(t0, t1), pk(t2, t3));
      }
      if (do_stage)
        *(uint2*)&ibuf[cur ^ 1][srow * IP + (xhalf ? 0 : 64) + sc4 * 4] =
            make_uint2(pk(nv[0], nv[1]), pk(nv[2], nv[3]));
      cur ^= 1;
    }
  }

  // ---------------- state-space rollout (K = 320) + fused y = C h ----------------
  {
    short8 sf[2][10];
#pragma unroll
    for (int mt = 0; mt < 2; ++mt)
#pragma unroll
      for (int kf = 0; kf < 10; ++kf)
        sf[mt][kf] = *(const short8*)(ws + U_WSS +
                       (size_t)(w * 32 + mt * 16 + col) * 320 + kf * 32 + q * 8);
    f32x4 bs[2];
#pragma unroll
    for (int mt = 0; mt < 2; ++mt)
      bs[mt] = *(const f32x4*)(fbias + 256 + w * 32 + mt * 16 + q * 4);
    short8 cf[8];
    f32x4 cb;
    if (w < 4) {
#pragma unroll
      for (int kf = 0; kf < 8; ++kf)
        cf[kf] = *(const short8*)(ws + U_C + (size_t)(w * 16 + col) * 256 + kf * 32 + q * 8);
      cb = *(const f32x4*)(C_b + w * 16 + q * 4);
    }

    for (int i = 0; i < T_FWD; ++i) {
      f32x4 nv;
      if (i < T_FWD - 1 && xhalf)
        nv = *(const f32x4*)(fwd_x + ((size_t)(i + 1) * BATCHN + r0 + srow) * 64 + sc4 * 4);
      __syncthreads();  // h_i (hbuf[cur]) and x_i (ibuf[cur]) visible
      const unsigned short* hc = hbuf[cur];
      const unsigned short* ic = ibuf[cur];
      short8 bfr[10];
#pragma unroll
      for (int kf = 0; kf < 8; ++kf)
        bfr[kf] = *(const short8*)&hc[col * HP + kf * 32 + q * 8];
#pragma unroll
      for (int kf = 8; kf < 10; ++kf)
        bfr[kf] = *(const short8*)&ic[col * IP + (kf - 8) * 32 + q * 8];
      f32x4 acc[2];
#pragma unroll
      for (int mt = 0; mt < 2; ++mt) acc[mt] = bs[mt];
#pragma unroll
      for (int kf = 0; kf < 10; ++kf)
#pragma unroll
        for (int mt = 0; mt < 2; ++mt)
          acc[mt] = __builtin_amdgcn_mfma_f32_16x16x32_bf16(sf[mt][kf], bfr[kf], acc[mt], 0, 0, 0);
      if (w < 4 && i >= 1) {  // y_i = C h_i + C_b (h_i = this step's B-frags)
        f32x4 y = cb;
#pragma unroll
        for (int kf = 0; kf < 8; ++kf)
          y = __builtin_amdgcn_mfma_f32_16x16x32_bf16(cf[kf], bfr[kf], y, 0, 0, 0);
        *(f32x4*)(out + ((size_t)(i - 1) * BATCHN + r0 + col) * 64 + w * 16 + q * 4) = y;
      }
      unsigned short* hn_ = hbuf[cur ^ 1];
#pragma unroll
      for (int mt = 0; mt < 2; ++mt)
        *(uint2*)&hn_[col * HP + w * 32 + mt * 16 + q * 4] =
            make_uint2(pk(acc[mt][0], acc[mt][1]), pk(acc[mt][2], acc[mt][3]));
      if (i < T_FWD - 1 && xhalf)
        *(uint2*)&ibuf[cur ^ 1][srow * IP + sc4 * 4] =
            make_uint2(pk(nv[0], nv[1]), pk(nv[2], nv[3]));
      cur ^= 1;
    }

    // epilogue: y_80 from h_80
    __syncthreads();
    if (w < 4) {
      const unsigned short* hc = hbuf[cur];
      short8 bfr[8];
#pragma unroll
      for (int kf = 0; kf < 8; ++kf)
        bfr[kf] = *(const short8*)&hc[col * HP + kf * 32 + q * 8];
      f32x4 y = cb;
#pragma unroll
      for (int kf = 0; kf < 8; ++kf)
        y = __builtin_amdgcn_mfma_f32_16x16x32_bf16(cf[kf], bfr[kf], y, 0, 0, 0);
      *(f32x4*)(out + ((size_t)(T_FWD - 1) * BATCHN + r0 + col) * 64 + w * 16 + q * 4) = y;
    }
  }
}

extern "C" void kernel_launch(void* const* d_in, const int* in_sizes, int n_in,
                              void* d_out, int out_size, void* d_ws, size_t ws_size,
                              hipStream_t stream) {
  const float* pre_x = (const float*)d_in[0];
  const float* pre_y = (const float*)d_in[1];
  const float* fwd_x = (const float*)d_in[2];
  const float* A_w   = (const float*)d_in[3];
  const float* A_b   = (const float*)d_in[4];
  const float* B_w   = (const float*)d_in[5];
  const float* B_b   = (const float*)d_in[6];
  const float* C_w   = (const float*)d_in[7];
  const float* C_b   = (const float*)d_in[8];
  const float* W_ih  = (const float*)d_in[9];
  const float* b_ih  = (const float*)d_in[10];
  const float* W_hh  = (const float*)d_in[11];
  const float* b_hh  = (const float*)d_in[12];
  unsigned short* ws = (unsigned short*)d_ws;
  float* out = (float*)d_out;

  prep_kernel<<<(PREP_N + 255) / 256, 256, 0, stream>>>(
      A_w, A_b, B_w, B_b, C_w, W_ih, b_ih, W_hh, b_hh, ws);
  rnn_ss_kernel<<<BATCHN / 16, 512, 0, stream>>>(pre_x, pre_y, fwd_x, C_b, ws, out);
}